// Round 2
// baseline (60.794 us; speedup 1.0000x reference)
//
#include <hip/hip_runtime.h>

// Problem constants (from reference setup_inputs): B=4, N=4096, D=128.
constexpr int BATCH = 4;
constexpr int N = 4096;
constexpr int D = 128;

// native clang vector type (HIP's float4 is a class — rejected by
// __builtin_nontemporal_store)
typedef float vfloat4 __attribute__((ext_vector_type(4)));

// ---------------------------------------------------------------------------
// Kernel 1: per-row dual dot products.
//   A[b*N+n] = dot(E[b,n,:], W[0:128]);  Bv[b*N+n] = dot(E[b,n,:], W[128:256])
// One 64-lane wave per row; each lane handles 2 consecutive floats (float2),
// then a butterfly __shfl_xor reduction across the wave.
// ---------------------------------------------------------------------------
__global__ void dots_kernel(const float* __restrict__ E,
                            const float* __restrict__ W,
                            float* __restrict__ A,
                            float* __restrict__ Bv) {
    const int gtid = blockIdx.x * blockDim.x + threadIdx.x;
    const int wave = gtid >> 6;          // global wave id = row id
    const int lane = threadIdx.x & 63;
    if (wave >= BATCH * N) return;

    const float* row = E + (size_t)wave * D;
    const float2 e  = *reinterpret_cast<const float2*>(row + lane * 2);
    const float2 wi = *reinterpret_cast<const float2*>(W + lane * 2);
    const float2 wj = *reinterpret_cast<const float2*>(W + D + lane * 2);

    float pa = e.x * wi.x + e.y * wi.y;
    float pb = e.x * wj.x + e.y * wj.y;

    // full-wave butterfly reduce (64 lanes)
    #pragma unroll
    for (int off = 32; off >= 1; off >>= 1) {
        pa += __shfl_xor(pa, off);
        pb += __shfl_xor(pb, off);
    }
    if (lane == 0) {
        A[wave]  = pa;
        Bv[wave] = pb;
    }
}

// ---------------------------------------------------------------------------
// Kernel 2: outer-sum materialization (write-bound, 268 MB).
//   out[b][i][j] = A[b*N+i] + Bv[b*N+j]
// vfloat4 (native vector) stores, 16 B/lane. Power-of-2 index math:
//   N = 4096 = 2^12, J4 = N/4 = 1024 = 2^10, N*J4 = 2^22.
// a-load is uniform across 1024 consecutive threads (broadcast);
// b-loads hit L1/L2 (16 KB per batch). Non-temporal output stores:
// output is write-once, never re-read on device.
// ---------------------------------------------------------------------------
__global__ void outer_kernel(const float* __restrict__ A,
                             const float* __restrict__ Bv,
                             vfloat4* __restrict__ out) {
    constexpr int J4 = N / 4;                       // 1024
    const size_t total4 = (size_t)BATCH * N * J4;   // 16,777,216 float4s
    const size_t stride = (size_t)gridDim.x * blockDim.x;

    for (size_t idx = (size_t)blockIdx.x * blockDim.x + threadIdx.x;
         idx < total4; idx += stride) {
        const int j4    = (int)(idx & (J4 - 1));
        const int i     = (int)((idx >> 10) & (N - 1));
        const int batch = (int)(idx >> 22);

        const float a = A[batch * N + i];
        const vfloat4 b4 = reinterpret_cast<const vfloat4*>(Bv)[batch * J4 + j4];

        vfloat4 v;
        v.x = a + b4.x;
        v.y = a + b4.y;
        v.z = a + b4.z;
        v.w = a + b4.w;
        __builtin_nontemporal_store(v, &out[idx]);
    }
}

extern "C" void kernel_launch(void* const* d_in, const int* in_sizes, int n_in,
                              void* d_out, int out_size, void* d_ws, size_t ws_size,
                              hipStream_t stream) {
    const float* E = (const float*)d_in[0];   // (4, 4096, 128) f32
    const float* W = (const float*)d_in[1];   // (1, 256) f32

    // workspace: A (16384 f32) then Bv (16384 f32) = 128 KB
    float* A  = (float*)d_ws;
    float* Bv = A + (size_t)BATCH * N;

    // Kernel 1: 16384 rows, 1 wave/row, 4 waves (256 threads)/block
    {
        const int threads = 256;
        const int rows = BATCH * N;
        const int blocks = rows / (threads / 64);   // 4096
        dots_kernel<<<blocks, threads, 0, stream>>>(E, W, A, Bv);
    }

    // Kernel 2: grid-stride over 16,777,216 float4 stores
    {
        const int threads = 256;
        const int blocks = 4096;    // 16 float4s per thread
        outer_kernel<<<blocks, threads, 0, stream>>>(A, Bv, (vfloat4*)d_out);
    }
}

// Round 3
// 58.600 us; speedup vs baseline: 1.0374x; 1.0374x over previous
//
#include <hip/hip_runtime.h>

// Problem constants (from reference setup_inputs): B=4, N=4096, D=128.
constexpr int BATCH = 4;
constexpr int N = 4096;
constexpr int D = 128;
constexpr int J4 = N / 4;             // 1024 float4s per output row
constexpr int ROWS_PER_BLOCK = 4;     // rows of out per block (share one batch)

// native clang vector type (HIP's float4 is a class — rejected by
// __builtin_nontemporal_store)
typedef float vfloat4 __attribute__((ext_vector_type(4)));

// ---------------------------------------------------------------------------
// Kernel 1: per-row dual dot products.
//   A[b*N+n] = dot(E[b,n,:], W[0:128]);  Bv[b*N+n] = dot(E[b,n,:], W[128:256])
// One 64-lane wave per row; each lane handles 2 consecutive floats (float2),
// then a butterfly __shfl_xor reduction across the wave.
// ---------------------------------------------------------------------------
__global__ void dots_kernel(const float* __restrict__ E,
                            const float* __restrict__ W,
                            float* __restrict__ A,
                            float* __restrict__ Bv) {
    const int gtid = blockIdx.x * blockDim.x + threadIdx.x;
    const int wave = gtid >> 6;          // global wave id = row id
    const int lane = threadIdx.x & 63;
    if (wave >= BATCH * N) return;

    const float* row = E + (size_t)wave * D;
    const float2 e  = *reinterpret_cast<const float2*>(row + lane * 2);
    const float2 wi = *reinterpret_cast<const float2*>(W + lane * 2);
    const float2 wj = *reinterpret_cast<const float2*>(W + D + lane * 2);

    float pa = e.x * wi.x + e.y * wi.y;
    float pb = e.x * wj.x + e.y * wj.y;

    // full-wave butterfly reduce (64 lanes)
    #pragma unroll
    for (int off = 32; off >= 1; off >>= 1) {
        pa += __shfl_xor(pa, off);
        pb += __shfl_xor(pb, off);
    }
    if (lane == 0) {
        A[wave]  = pa;
        Bv[wave] = pb;
    }
}

// ---------------------------------------------------------------------------
// Kernel 2: outer-sum materialization (write-bound, 268 MB).
//   out[row][j] = A[row] + Bv[(row>>12)*N + j]   (row = b*N+i, 16384 rows)
// Each block owns ROWS_PER_BLOCK=4 consecutive rows (same batch since 4|N):
//   - a[0..3] are block-uniform -> scalar loads, hoisted out of the loop
//   - each Bv float4 loaded ONCE per thread, reused for 4 row stores
//   - per-store index math ~1 add; stores 1 KB/wave contiguous, 4 streams
// Non-temporal stores: output is write-once, never re-read on device.
// ---------------------------------------------------------------------------
__global__ void outer_kernel(const float* __restrict__ A,
                             const float* __restrict__ Bv,
                             vfloat4* __restrict__ out) {
    const int row0  = blockIdx.x * ROWS_PER_BLOCK;      // global row
    const int batch = row0 >> 12;                       // row / 4096
    const vfloat4* __restrict__ bv4 =
        reinterpret_cast<const vfloat4*>(Bv) + (size_t)batch * J4;

    float a[ROWS_PER_BLOCK];
    #pragma unroll
    for (int r = 0; r < ROWS_PER_BLOCK; ++r) a[r] = A[row0 + r];

    #pragma unroll
    for (int k = 0; k < J4 / 256; ++k) {                // 4 iterations
        const int j4 = threadIdx.x + k * 256;
        const vfloat4 b4 = bv4[j4];
        #pragma unroll
        for (int r = 0; r < ROWS_PER_BLOCK; ++r) {
            vfloat4 v = b4 + a[r];                      // scalar broadcast add
            __builtin_nontemporal_store(v, &out[(size_t)(row0 + r) * J4 + j4]);
        }
    }
}

extern "C" void kernel_launch(void* const* d_in, const int* in_sizes, int n_in,
                              void* d_out, int out_size, void* d_ws, size_t ws_size,
                              hipStream_t stream) {
    const float* E = (const float*)d_in[0];   // (4, 4096, 128) f32
    const float* W = (const float*)d_in[1];   // (1, 256) f32

    // workspace: A (16384 f32) then Bv (16384 f32) = 128 KB
    float* A  = (float*)d_ws;
    float* Bv = A + (size_t)BATCH * N;

    // Kernel 1: 16384 rows, 1 wave/row, 4 waves (256 threads)/block
    {
        const int threads = 256;
        const int rows = BATCH * N;
        const int blocks = rows / (threads / 64);   // 4096
        dots_kernel<<<blocks, threads, 0, stream>>>(E, W, A, Bv);
    }

    // Kernel 2: 16384 rows / 4 rows-per-block = 4096 blocks
    {
        const int threads = 256;
        const int blocks = (BATCH * N) / ROWS_PER_BLOCK;   // 4096
        outer_kernel<<<blocks, threads, 0, stream>>>(A, Bv, (vfloat4*)d_out);
    }
}

// Round 4
// 49.576 us; speedup vs baseline: 1.2263x; 1.1820x over previous
//
#include <hip/hip_runtime.h>

// Problem constants (from reference setup_inputs): B=4, N=4096, D=128.
constexpr int BATCH = 4;
constexpr int N = 4096;
constexpr int D = 128;
constexpr int J4 = N / 4;             // 1024 float4s per output row
constexpr int ROWS_PER_BLOCK = 8;     // rows of out per block (share one batch)

typedef float vfloat4 __attribute__((ext_vector_type(4)));

// ---------------------------------------------------------------------------
// Kernel 1: per-row dual dot products, v2.
//   A[row] = dot(E[row,:], W[0:128]);  Bv[row] = dot(E[row,:], W[128:256])
// Each wave handles TWO rows: lanes 0-31 -> row 2w, lanes 32-63 -> row 2w+1.
// Each lane loads one float4 (16 B) -> 1 KB/wave fully coalesced.
// Butterfly reduce with offsets 16..1 stays within each 32-lane half.
// ---------------------------------------------------------------------------
__global__ void dots_kernel(const float* __restrict__ E,
                            const float* __restrict__ W,
                            float* __restrict__ A,
                            float* __restrict__ Bv) {
    const int gtid = blockIdx.x * blockDim.x + threadIdx.x;
    const int wave = gtid >> 6;
    const int lane = threadIdx.x & 63;
    const int half = lane >> 5;          // 0 or 1
    const int c    = lane & 31;          // float4 index within row
    const int row  = wave * 2 + half;
    if (row >= BATCH * N) return;

    const vfloat4 e4 = *reinterpret_cast<const vfloat4*>(E + (size_t)row * D + c * 4);
    const vfloat4 wi = *reinterpret_cast<const vfloat4*>(W + c * 4);
    const vfloat4 wj = *reinterpret_cast<const vfloat4*>(W + D + c * 4);

    float pa = e4.x * wi.x + e4.y * wi.y + e4.z * wi.z + e4.w * wi.w;
    float pb = e4.x * wj.x + e4.y * wj.y + e4.z * wj.z + e4.w * wj.w;

    // reduce across the 32-lane half (xor offsets <32 stay within the half)
    #pragma unroll
    for (int off = 16; off >= 1; off >>= 1) {
        pa += __shfl_xor(pa, off);
        pb += __shfl_xor(pb, off);
    }
    if (c == 0) {
        A[row]  = pa;
        Bv[row] = pb;
    }
}

// ---------------------------------------------------------------------------
// Kernel 2: outer-sum materialization (write-bound, 268 MB).
//   out[row][j] = A[row] + Bv[(row>>12)*N + j]
// Each block owns 8 consecutive rows (same batch since 8|N):
//   - a[0..7] block-uniform scalar loads, hoisted
//   - each Bv float4 loaded once, reused for 8 row stores
//   - PLAIN stores this round (A/B vs nontemporal: poison-fills reach
//     6.9 TB/s with plain stores through L2)
// Grid 2048 blocks x 256 thr = 8 wg/CU = full 32 waves/CU.
// ---------------------------------------------------------------------------
__global__ void outer_kernel(const float* __restrict__ A,
                             const float* __restrict__ Bv,
                             vfloat4* __restrict__ out) {
    const int row0  = blockIdx.x * ROWS_PER_BLOCK;
    const int batch = row0 >> 12;                       // row / 4096
    const vfloat4* __restrict__ bv4 =
        reinterpret_cast<const vfloat4*>(Bv) + (size_t)batch * J4;

    float a[ROWS_PER_BLOCK];
    #pragma unroll
    for (int r = 0; r < ROWS_PER_BLOCK; ++r) a[r] = A[row0 + r];

    #pragma unroll
    for (int k = 0; k < J4 / 256; ++k) {                // 4 iterations
        const int j4 = threadIdx.x + k * 256;
        const vfloat4 b4 = bv4[j4];
        #pragma unroll
        for (int r = 0; r < ROWS_PER_BLOCK; ++r) {
            out[(size_t)(row0 + r) * J4 + j4] = b4 + a[r];
        }
    }
}

extern "C" void kernel_launch(void* const* d_in, const int* in_sizes, int n_in,
                              void* d_out, int out_size, void* d_ws, size_t ws_size,
                              hipStream_t stream) {
    const float* E = (const float*)d_in[0];   // (4, 4096, 128) f32
    const float* W = (const float*)d_in[1];   // (1, 256) f32

    // workspace: A (16384 f32) then Bv (16384 f32) = 128 KB
    float* A  = (float*)d_ws;
    float* Bv = A + (size_t)BATCH * N;

    // Kernel 1: 16384 rows, 2 rows/wave, 4 waves/block -> 2048 blocks
    {
        const int threads = 256;
        const int blocks = (BATCH * N) / 8;   // 2048
        dots_kernel<<<blocks, threads, 0, stream>>>(E, W, A, Bv);
    }

    // Kernel 2: 16384 rows / 8 rows-per-block = 2048 blocks
    {
        const int threads = 256;
        const int blocks = (BATCH * N) / ROWS_PER_BLOCK;   // 2048
        outer_kernel<<<blocks, threads, 0, stream>>>(A, Bv, (vfloat4*)d_out);
    }
}